// Round 1
// baseline (293.105 us; speedup 1.0000x reference)
//
#include <hip/hip_runtime.h>

typedef unsigned short u16;
typedef unsigned int u32;
typedef __bf16 bf16x8 __attribute__((ext_vector_type(8)));
typedef float f32x4 __attribute__((ext_vector_type(4)));

#define MFMA_BF16(a, b, c) __builtin_amdgcn_mfma_f32_16x16x32_bf16((a), (b), (c), 0, 0, 0)

// log2-domain constants
#define QSCALE 0.18033688011112042f   // 0.125 * log2(e): folded into w_qkv Q-rows at prep
#define M0SHIFT 24.0f                 // fixed softmax shift (log2 domain)

// ---------- helpers ----------

__device__ __forceinline__ u16 f2bf(float f) {
  u32 u = __builtin_bit_cast(u32, f);
  u += 0x7fffu + ((u >> 16) & 1u);   // RNE
  return (u16)(u >> 16);
}

__device__ __forceinline__ void async_copy16(const void* g, void* l) {
  __builtin_amdgcn_global_load_lds(
      (__attribute__((address_space(1))) void*)g,
      (__attribute__((address_space(3))) void*)l, 16, 0, 0);
}

// ---------- kernel 0: fused fp32->bf16 converts + RoPE cos/sin table ----------
// blocks [0, 12288): convert x (8192), w_qkv (3072, Q-rows pre-scaled), w_o (1024).
// blocks [12288, 12544): build rope table [2048][32] float2 (cos, sin).

__global__ __launch_bounds__(256) void prep_kernel(
    const float* __restrict__ x_f, const float* __restrict__ wqkv_f,
    const float* __restrict__ wo_f, u16* __restrict__ xb,
    u16* __restrict__ wqkvb, u16* __restrict__ wob, float2* __restrict__ rope_t) {
  const int blk = blockIdx.x;
  if (blk < 12288) {
    const float* src;
    u16* dst;
    int base;
    float scale = 1.0f;
    if (blk < 8192)      { src = x_f;    dst = xb;    base = blk; }
    else if (blk < 11264){ src = wqkv_f; dst = wqkvb; base = blk - 8192;
                           if (base < 1024) scale = QSCALE; }  // Q rows
    else                 { src = wo_f;   dst = wob;   base = blk - 11264; }
    const int i = base * 1024 + threadIdx.x * 4;
    const float4 v = *(const float4*)(src + i);
    ushort4 o;
    o.x = f2bf(v.x * scale); o.y = f2bf(v.y * scale);
    o.z = f2bf(v.z * scale); o.w = f2bf(v.w * scale);
    *(ushort4*)(dst + i) = o;
  } else {
    const int idx = (blk - 12288) * 256 + threadIdx.x;  // [0, 65536)
    const int s = idx >> 5, i = idx & 31;
    const float invf = __builtin_amdgcn_exp2f(-(float)i * 0.41524101186092027f);
    float rev = (float)s * invf * 0.15915494309189535f;  // radians -> revolutions
    rev -= floorf(rev);
    rope_t[idx] = make_float2(__builtin_amdgcn_cosf(rev), __builtin_amdgcn_sinf(rev));
  }
}

// ---------- shared 128x128 GEMM-BT tile core (m97 structure) ----------

__device__ __forceinline__ void gemm_bt_tile(const u16* A, const u16* B, int K,
                                             int row0, int col0,
                                             u16* lds, f32x4 acc[4][4]) {
  const int tid = threadIdx.x;
  const int wave = tid >> 6;
  const int lane = tid & 63;
  const int fr = lane & 15;
  const int quad = lane >> 4;
  const int wm = (wave >> 1) * 64;
  const int wn = (wave & 1) * 64;
  u16* a_lds = lds;         // [128][32]
  u16* b_lds = lds + 4096;  // [128][32]

  f32x4 zero = {0.f, 0.f, 0.f, 0.f};
#pragma unroll
  for (int mt = 0; mt < 4; ++mt)
#pragma unroll
    for (int nt = 0; nt < 4; ++nt) acc[mt][nt] = zero;

  for (int k0 = 0; k0 < K; k0 += 32) {
    __syncthreads();
#pragma unroll
    for (int c = 0; c < 2; ++c) {
      const int ebase = wave * 1024 + c * 512;
      const int e = ebase + lane * 8;
      const int r = e >> 5;
      const int kk = e & 31;
      async_copy16(A + (size_t)(row0 + r) * K + k0 + kk, a_lds + ebase);
      async_copy16(B + (size_t)(col0 + r) * K + k0 + kk, b_lds + ebase);
    }
    __syncthreads();

    bf16x8 a_frag[4], b_frag[4];
#pragma unroll
    for (int t = 0; t < 4; ++t) {
      a_frag[t] = *(const bf16x8*)(a_lds + (wm + t * 16 + fr) * 32 + quad * 8);
      b_frag[t] = *(const bf16x8*)(b_lds + (wn + t * 16 + fr) * 32 + quad * 8);
    }
#pragma unroll
    for (int mt = 0; mt < 4; ++mt)
#pragma unroll
      for (int nt = 0; nt < 4; ++nt)
        acc[mt][nt] = MFMA_BF16(a_frag[mt], b_frag[nt], acc[mt][nt]);
  }
}

// ---------- kernel 1: QKV projection + RoPE, coalesced LDS-bounce epilogue ----
// Q (pre-scaled via W), K -> [B][H][S][64]; V -> [B][H][64][S] (transposed).
// Each block is purely one region (col0 block-uniform).

__global__ __launch_bounds__(256) void qkv_rope_kernel(
    const u16* __restrict__ x, const u16* __restrict__ w_qkv,
    const float2* __restrict__ rope_t,
    u16* __restrict__ q_ws, u16* __restrict__ k_ws, u16* __restrict__ vt_ws) {
  __shared__ u16 sbuf[128 * 136];  // gemm uses first 8192; epilogue full tile
  f32x4 acc[4][4];
  const int row0 = blockIdx.y * 128;  // M = 8192
  const int col0 = blockIdx.x * 128;  // N = 3072
  gemm_bt_tile(x, w_qkv, 1024, row0, col0, sbuf, acc);

  const int tid = threadIdx.x;
  const int wave = tid >> 6, lane = tid & 63;
  const int fr = lane & 15, quad = lane >> 4;
  const int wm = (wave >> 1) * 64, wn = (wave & 1) * 64;
  const int region = col0 >> 10;      // 0=Q 1=K 2=V (block-uniform)
  const int f0 = col0 & 1023;
  const int s0r = row0 & 2047;
  const int bb = row0 >> 11;

  __syncthreads();  // all waves done reading gemm LDS

  if (region < 2) {
    // rotate in registers, stage [m][n] (stride 136)
#pragma unroll
    for (int mt = 0; mt < 4; ++mt) {
#pragma unroll
      for (int nt = 0; nt < 4; ++nt) {
        const int n = wn + nt * 16 + fr;
        const int d = n & 63;  // f0 is 128-aligned
#pragma unroll
        for (int r = 0; r < 4; ++r) {
          const int m = wm + mt * 16 + quad * 4 + r;
          const float own = acc[mt][nt][r];
          const float part = __shfl_xor(own, 1);
          const int s = s0r + m;
          const float2 cssn = rope_t[s * 32 + (d >> 1)];
          const float val = (d & 1) ? (part * cssn.y + own * cssn.x)
                                    : (own * cssn.x - part * cssn.y);
          sbuf[m * 136 + n] = f2bf(val);
        }
      }
    }
    __syncthreads();
    u16* dst = (region == 0) ? q_ws : k_ws;
    const int h0 = f0 >> 6;
#pragma unroll
    for (int j = 0; j < 8; ++j) {
      const int idx2 = j * 256 + tid;       // 0..2047
      const int hf = idx2 >> 10;            // head half
      const int m = (idx2 & 1023) >> 3;
      const int c8 = (idx2 & 7) * 8;
      const uint4 v = *(const uint4*)(sbuf + m * 136 + hf * 64 + c8);
      *(uint4*)(dst + ((size_t)(bb * 16 + h0 + hf) * 2048 + s0r + m) * 64 + c8) = v;
    }
  } else {
    // stage transposed [n][m] (stride 136)
#pragma unroll
    for (int mt = 0; mt < 4; ++mt)
#pragma unroll
      for (int nt = 0; nt < 4; ++nt) {
        const int n = wn + nt * 16 + fr;
#pragma unroll
        for (int r = 0; r < 4; ++r) {
          const int m = wm + mt * 16 + quad * 4 + r;
          sbuf[n * 136 + m] = f2bf(acc[mt][nt][r]);
        }
      }
    __syncthreads();
    const int h0 = f0 >> 6;
#pragma unroll
    for (int j = 0; j < 8; ++j) {
      const int idx2 = j * 256 + tid;       // 0..2047
      const int n = idx2 >> 4;              // 0..127
      const int mc = (idx2 & 15) * 8;
      const int h = h0 + (n >> 6);
      const int d = n & 63;
      const uint4 v = *(const uint4*)(sbuf + n * 136 + mc);
      *(uint4*)(vt_ws + ((size_t)(bb * 16 + h) * 64 + d) * 2048 + s0r + mc) = v;
    }
  }
}

// ---------- kernel 2: causal flash attention (fixed-shift log2 softmax) ------
// grid 1024: idx = qt_rev*64 + bh (same-bh blocks share an XCD slot; longest
// q-tiles first). block 256 = 4 waves; wave owns 32 q rows. K-tile 64.
// LDS ~36KB -> 4 blocks/CU.

__global__ __launch_bounds__(256, 4) void flash_attn_kernel(
    const u16* __restrict__ Q, const u16* __restrict__ K, const u16* __restrict__ Vt,
    const int* __restrict__ pad, u16* __restrict__ O) {
  const int S = 2048;
  const int idx = blockIdx.x;
  const int bh = idx & 63;
  const int b = bh >> 4, h = bh & 15;
  const int q0 = (15 - (idx >> 6)) * 128;
  const u16* Qh = Q + (size_t)bh * S * 64;
  const u16* Kh = K + (size_t)bh * S * 64;
  const u16* Vth = Vt + (size_t)bh * 64 * S;
  const int tid = threadIdx.x, wave = tid >> 6, lane = tid & 63;
  const int fr = lane & 15, quad = lane >> 4;

  __shared__ u16 lds_k[2 * 64 * 32];    // [kc][kpos 64][d 32]   8 KB
  __shared__ u16 lds_vt[2 * 64 * 32];   // [kc][d 64][kpos 32]   8 KB
  __shared__ u16 lds_p[4][32 * 76];     // per-wave [q 32][76]  19 KB
  __shared__ float lds_bias[64];

  const int qb = q0 + wave * 32;  // wave's first q row
  bf16x8 qfrag[2][2];
#pragma unroll
  for (int mt = 0; mt < 2; ++mt)
#pragma unroll
    for (int kk = 0; kk < 2; ++kk)
      qfrag[mt][kk] =
          *(const bf16x8*)(Qh + (size_t)(qb + mt * 16 + fr) * 64 + kk * 32 + quad * 8);

  bf16x8 ones;
#pragma unroll
  for (int j = 0; j < 8; ++j) ones[j] = (__bf16)1.0f;

  f32x4 zero = {0.f, 0.f, 0.f, 0.f};
  f32x4 o_acc[2][4], lacc[2];
#pragma unroll
  for (int mt = 0; mt < 2; ++mt) {
    lacc[mt] = zero;
#pragma unroll
    for (int nt = 0; nt < 4; ++nt) o_acc[mt][nt] = zero;
  }

  u16* pw = lds_p[wave];
  const float NEG = -__builtin_inff();

  for (int k0 = 0; k0 <= q0 + 64; k0 += 64) {
    __syncthreads();  // prior iter's LDS reads done
#pragma unroll
    for (int it = 0; it < 2; ++it) {
      const int slot = it * 256 + tid;
      const int row = tid >> 2;
      const int c8 = (tid & 3) * 8;
      async_copy16(Kh + (size_t)(k0 + row) * 64 + it * 32 + c8, lds_k + slot * 8);
      async_copy16(Vth + (size_t)row * 2048 + k0 + it * 32 + c8, lds_vt + slot * 8);
    }
    if (tid < 64) lds_bias[tid] = pad[b * S + k0 + tid] ? -M0SHIFT : NEG;
    __syncthreads();  // vmcnt drained

    if (k0 <= qb + 31) {  // wave-uniform: skip fully-masked tiles
      const bool needMask = (k0 + 63 > qb);
#pragma unroll
      for (int nt = 0; nt < 4; ++nt) {
        f32x4 s0 = zero, s1 = zero;
#pragma unroll
        for (int kk = 0; kk < 2; ++kk) {
          bf16x8 bfrag =
              *(const bf16x8*)(lds_k + (kk * 64 + nt * 16 + fr) * 32 + quad * 8);
          s0 = MFMA_BF16(qfrag[0][kk], bfrag, s0);
          s1 = MFMA_BF16(qfrag[1][kk], bfrag, s1);
        }
        const float bias = lds_bias[nt * 16 + fr];
        const int col = k0 + nt * 16 + fr;
#pragma unroll
        for (int r = 0; r < 4; ++r) {
          float v0 = s0[r] + bias;
          float v1 = s1[r] + bias;
          if (needMask) {
            if (col > qb + quad * 4 + r) v0 = NEG;
            if (col > qb + 16 + quad * 4 + r) v1 = NEG;
          }
          const float p0 = __builtin_amdgcn_exp2f(v0);
          const float p1 = __builtin_amdgcn_exp2f(v1);
          pw[(quad * 4 + r) * 76 + nt * 16 + fr] =
              (u16)(__builtin_bit_cast(u32, p0) >> 16);
          pw[(16 + quad * 4 + r) * 76 + nt * 16 + fr] =
              (u16)(__builtin_bit_cast(u32, p1) >> 16);
        }
      }
      // per-wave P bounce complete before A-frag reads (wave-private buffer)
      asm volatile("s_waitcnt lgkmcnt(0)" ::: "memory");

#pragma unroll
      for (int kk = 0; kk < 2; ++kk) {
        bf16x8 p0 = *(const bf16x8*)(pw + fr * 76 + kk * 32 + quad * 8);
        bf16x8 p1 = *(const bf16x8*)(pw + (16 + fr) * 76 + kk * 32 + quad * 8);
        lacc[0] = MFMA_BF16(p0, ones, lacc[0]);
        lacc[1] = MFMA_BF16(p1, ones, lacc[1]);
#pragma unroll
        for (int nt = 0; nt < 4; ++nt) {
          bf16x8 vf =
              *(const bf16x8*)(lds_vt + (kk * 64 + nt * 16 + fr) * 32 + quad * 8);
          o_acc[0][nt] = MFMA_BF16(p0, vf, o_acc[0][nt]);
          o_acc[1][nt] = MFMA_BF16(p1, vf, o_acc[1][nt]);
        }
      }
    }
  }

  // epilogue: normalize, write [B][S][H*64]
#pragma unroll
  for (int mt = 0; mt < 2; ++mt)
#pragma unroll
    for (int r = 0; r < 4; ++r) {
      const int row = qb + mt * 16 + quad * 4 + r;
      const float l = lacc[mt][r];
      const float rl = (l > 0.f) ? (1.0f / l) : 0.f;
#pragma unroll
      for (int nt = 0; nt < 4; ++nt)
        O[(size_t)(b * S + row) * 1024 + h * 64 + nt * 16 + fr] =
            f2bf(o_acc[mt][nt][r] * rl);
    }
}

// ---------- kernel 3: output projection (writes fp32 to d_out) ----------

__global__ __launch_bounds__(256) void oproj_kernel(
    const u16* __restrict__ A, const u16* __restrict__ w_o, float* __restrict__ out) {
  __shared__ u16 lds[8192];
  f32x4 acc[4][4];
  const int row0 = blockIdx.y * 128;
  const int col0 = blockIdx.x * 128;
  gemm_bt_tile(A, w_o, 1024, row0, col0, lds, acc);
  const int tid = threadIdx.x;
  const int wave = tid >> 6, lane = tid & 63;
  const int fr = lane & 15, quad = lane >> 4;
  const int wm = (wave >> 1) * 64, wn = (wave & 1) * 64;
#pragma unroll
  for (int mt = 0; mt < 4; ++mt)
#pragma unroll
    for (int nt = 0; nt < 4; ++nt) {
      const int ncol = col0 + wn + nt * 16 + fr;
#pragma unroll
      for (int r = 0; r < 4; ++r) {
        const int mrow = row0 + wm + mt * 16 + quad * 4 + r;
        out[(size_t)mrow * 1024 + ncol] = acc[mt][nt][r];
      }
    }
}

// ---------- launch ----------

extern "C" void kernel_launch(void* const* d_in, const int* in_sizes, int n_in,
                              void* d_out, int out_size, void* d_ws, size_t ws_size,
                              hipStream_t stream) {
  const float* x_f = (const float*)d_in[0];     // [4][2048][1024] fp32
  const int* pad = (const int*)d_in[1];         // [4][2048] int32
  const float* wqkv_f = (const float*)d_in[2];  // [3072][1024] fp32
  const float* wo_f = (const float*)d_in[3];    // [1024][1024] fp32
  float* out = (float*)d_out;                   // [4][2048][1024] fp32

  const int NX = 4 * 2048 * 1024;
  const int NWQKV = 3072 * 1024;
  const int NWO = 1024 * 1024;
  const size_t HSZ = (size_t)4 * 16 * 2048 * 64;  // 8M elems per head-tensor

  u16* xb = (u16*)d_ws;            // 16 MB
  u16* wqkvb = xb + NX;            // 6 MB
  u16* wob = wqkvb + NWQKV;        // 2 MB
  u16* q_ws = wob + NWO;           // 16 MB  [B][H][S][64] (pre-scaled, roped)
  u16* k_ws = q_ws + HSZ;          // 16 MB  [B][H][S][64] (roped)
  u16* vt_ws = k_ws + HSZ;         // 16 MB  [B][H][64][S] (transposed)
  u16* attn_ws = vt_ws + HSZ;      // 16 MB  [B*S][D]
  float2* rope_t = (float2*)(attn_ws + HSZ);  // 512 KB [2048][32]

  dim3 blk(256);
  prep_kernel<<<dim3(12544), blk, 0, stream>>>(x_f, wqkv_f, wo_f, xb, wqkvb, wob, rope_t);
  qkv_rope_kernel<<<dim3(24, 64), blk, 0, stream>>>(xb, wqkvb, rope_t, q_ws, k_ws, vt_ws);
  flash_attn_kernel<<<dim3(1024), blk, 0, stream>>>(q_ws, k_ws, vt_ws, pad, attn_ws);
  oproj_kernel<<<dim3(8, 64), blk, 0, stream>>>(attn_ws, wob, out);
}

// Round 2
// 289.232 us; speedup vs baseline: 1.0134x; 1.0134x over previous
//
#include <hip/hip_runtime.h>

typedef unsigned short u16;
typedef unsigned int u32;
typedef __bf16 bf16x8 __attribute__((ext_vector_type(8)));
typedef float f32x4 __attribute__((ext_vector_type(4)));

#define MFMA_BF16(a, b, c) __builtin_amdgcn_mfma_f32_16x16x32_bf16((a), (b), (c), 0, 0, 0)

// log2-domain constants
#define QSCALE 0.18033688011112042f   // 0.125 * log2(e): folded into w_qkv Q-rows at prep
#define M0SHIFT 24.0f                 // fixed softmax shift (log2 domain)

// ---------- helpers ----------

__device__ __forceinline__ u16 f2bf(float f) {
  u32 u = __builtin_bit_cast(u32, f);
  u += 0x7fffu + ((u >> 16) & 1u);   // RNE
  return (u16)(u >> 16);
}

__device__ __forceinline__ void async_copy16(const void* g, void* l) {
  __builtin_amdgcn_global_load_lds(
      (__attribute__((address_space(1))) void*)g,
      (__attribute__((address_space(3))) void*)l, 16, 0, 0);
}

// ---------- kernel 0: fused fp32->bf16 converts + RoPE cos/sin table ----------
// blocks [0, 12288): convert x (8192), w_qkv (3072, Q-rows pre-scaled), w_o (1024).
// blocks [12288, 12544): build rope table [2048][32] float2 (cos, sin).

__global__ __launch_bounds__(256) void prep_kernel(
    const float* __restrict__ x_f, const float* __restrict__ wqkv_f,
    const float* __restrict__ wo_f, u16* __restrict__ xb,
    u16* __restrict__ wqkvb, u16* __restrict__ wob, float2* __restrict__ rope_t) {
  const int blk = blockIdx.x;
  if (blk < 12288) {
    const float* src;
    u16* dst;
    int base;
    float scale = 1.0f;
    if (blk < 8192)      { src = x_f;    dst = xb;    base = blk; }
    else if (blk < 11264){ src = wqkv_f; dst = wqkvb; base = blk - 8192;
                           if (base < 1024) scale = QSCALE; }  // Q rows
    else                 { src = wo_f;   dst = wob;   base = blk - 11264; }
    const int i = base * 1024 + threadIdx.x * 4;
    const float4 v = *(const float4*)(src + i);
    ushort4 o;
    o.x = f2bf(v.x * scale); o.y = f2bf(v.y * scale);
    o.z = f2bf(v.z * scale); o.w = f2bf(v.w * scale);
    *(ushort4*)(dst + i) = o;
  } else {
    const int idx = (blk - 12288) * 256 + threadIdx.x;  // [0, 65536)
    const int s = idx >> 5, i = idx & 31;
    const float invf = __builtin_amdgcn_exp2f(-(float)i * 0.41524101186092027f);
    float rev = (float)s * invf * 0.15915494309189535f;  // radians -> revolutions
    rev -= floorf(rev);
    rope_t[idx] = make_float2(__builtin_amdgcn_cosf(rev), __builtin_amdgcn_sinf(rev));
  }
}

// ---------- shared 128x128 GEMM-BT tile core (m97 structure) ----------

__device__ __forceinline__ void gemm_bt_tile(const u16* A, const u16* B, int K,
                                             int row0, int col0,
                                             u16* lds, f32x4 acc[4][4]) {
  const int tid = threadIdx.x;
  const int wave = tid >> 6;
  const int lane = tid & 63;
  const int fr = lane & 15;
  const int quad = lane >> 4;
  const int wm = (wave >> 1) * 64;
  const int wn = (wave & 1) * 64;
  u16* a_lds = lds;         // [128][32]
  u16* b_lds = lds + 4096;  // [128][32]

  f32x4 zero = {0.f, 0.f, 0.f, 0.f};
#pragma unroll
  for (int mt = 0; mt < 4; ++mt)
#pragma unroll
    for (int nt = 0; nt < 4; ++nt) acc[mt][nt] = zero;

  for (int k0 = 0; k0 < K; k0 += 32) {
    __syncthreads();
#pragma unroll
    for (int c = 0; c < 2; ++c) {
      const int ebase = wave * 1024 + c * 512;
      const int e = ebase + lane * 8;
      const int r = e >> 5;
      const int kk = e & 31;
      async_copy16(A + (size_t)(row0 + r) * K + k0 + kk, a_lds + ebase);
      async_copy16(B + (size_t)(col0 + r) * K + k0 + kk, b_lds + ebase);
    }
    __syncthreads();

    bf16x8 a_frag[4], b_frag[4];
#pragma unroll
    for (int t = 0; t < 4; ++t) {
      a_frag[t] = *(const bf16x8*)(a_lds + (wm + t * 16 + fr) * 32 + quad * 8);
      b_frag[t] = *(const bf16x8*)(b_lds + (wn + t * 16 + fr) * 32 + quad * 8);
    }
#pragma unroll
    for (int mt = 0; mt < 4; ++mt)
#pragma unroll
      for (int nt = 0; nt < 4; ++nt)
        acc[mt][nt] = MFMA_BF16(a_frag[mt], b_frag[nt], acc[mt][nt]);
  }
}

// ---------- kernel 1: QKV projection + RoPE, coalesced LDS-bounce epilogue ----
// Q (pre-scaled via W), K -> [B][H][S][64]; V -> [B][H][64][S] (transposed).
// Each block is purely one region (col0 block-uniform).

__global__ __launch_bounds__(256) void qkv_rope_kernel(
    const u16* __restrict__ x, const u16* __restrict__ w_qkv,
    const float2* __restrict__ rope_t,
    u16* __restrict__ q_ws, u16* __restrict__ k_ws, u16* __restrict__ vt_ws) {
  __shared__ u16 sbuf[128 * 136];  // gemm uses first 8192; epilogue full tile
  f32x4 acc[4][4];
  const int row0 = blockIdx.y * 128;  // M = 8192
  const int col0 = blockIdx.x * 128;  // N = 3072
  gemm_bt_tile(x, w_qkv, 1024, row0, col0, sbuf, acc);

  const int tid = threadIdx.x;
  const int wave = tid >> 6, lane = tid & 63;
  const int fr = lane & 15, quad = lane >> 4;
  const int wm = (wave >> 1) * 64, wn = (wave & 1) * 64;
  const int region = col0 >> 10;      // 0=Q 1=K 2=V (block-uniform)
  const int f0 = col0 & 1023;
  const int s0r = row0 & 2047;
  const int bb = row0 >> 11;

  __syncthreads();  // all waves done reading gemm LDS

  if (region < 2) {
    // rotate in registers, stage [m][n] (stride 136)
#pragma unroll
    for (int mt = 0; mt < 4; ++mt) {
#pragma unroll
      for (int nt = 0; nt < 4; ++nt) {
        const int n = wn + nt * 16 + fr;
        const int d = n & 63;  // f0 is 128-aligned
#pragma unroll
        for (int r = 0; r < 4; ++r) {
          const int m = wm + mt * 16 + quad * 4 + r;
          const float own = acc[mt][nt][r];
          const float part = __shfl_xor(own, 1);
          const int s = s0r + m;
          const float2 cssn = rope_t[s * 32 + (d >> 1)];
          const float val = (d & 1) ? (part * cssn.y + own * cssn.x)
                                    : (own * cssn.x - part * cssn.y);
          sbuf[m * 136 + n] = f2bf(val);
        }
      }
    }
    __syncthreads();
    u16* dst = (region == 0) ? q_ws : k_ws;
    const int h0 = f0 >> 6;
#pragma unroll
    for (int j = 0; j < 8; ++j) {
      const int idx2 = j * 256 + tid;       // 0..2047
      const int hf = idx2 >> 10;            // head half
      const int m = (idx2 & 1023) >> 3;
      const int c8 = (idx2 & 7) * 8;
      const uint4 v = *(const uint4*)(sbuf + m * 136 + hf * 64 + c8);
      *(uint4*)(dst + ((size_t)(bb * 16 + h0 + hf) * 2048 + s0r + m) * 64 + c8) = v;
    }
  } else {
    // stage transposed [n][m] (stride 136)
#pragma unroll
    for (int mt = 0; mt < 4; ++mt)
#pragma unroll
      for (int nt = 0; nt < 4; ++nt) {
        const int n = wn + nt * 16 + fr;
#pragma unroll
        for (int r = 0; r < 4; ++r) {
          const int m = wm + mt * 16 + quad * 4 + r;
          sbuf[n * 136 + m] = f2bf(acc[mt][nt][r]);
        }
      }
    __syncthreads();
    const int h0 = f0 >> 6;
#pragma unroll
    for (int j = 0; j < 8; ++j) {
      const int idx2 = j * 256 + tid;       // 0..2047
      const int n = idx2 >> 4;              // 0..127
      const int mc = (idx2 & 15) * 8;
      const int h = h0 + (n >> 6);
      const int d = n & 63;
      const uint4 v = *(const uint4*)(sbuf + n * 136 + mc);
      *(uint4*)(vt_ws + ((size_t)(bb * 16 + h) * 64 + d) * 2048 + s0r + mc) = v;
    }
  }
}

// ---------- kernel 2: causal flash attention (fixed-shift log2 softmax) ------
// grid 1024: bh in low 6 bits (same-bh blocks share an XCD's L2).
// q-tile index permuted so each co-resident column {c, c+256, c+512, c+768}
// sums to uniform work (68 k-tile units) -> no long-CU tail.
// K/V LDS double-buffered: prefetch tile t+1 issued before compute of tile t,
// so the vmcnt(0) drain at the end-of-tile barrier waits on loads issued one
// full compute-tile earlier (T3 minimum 2-phase). LDS 52.2KB -> 3 blocks/CU.

__global__ __launch_bounds__(256, 3) void flash_attn_kernel(
    const u16* __restrict__ Q, const u16* __restrict__ K, const u16* __restrict__ Vt,
    const int* __restrict__ pad, u16* __restrict__ O) {
  const int S = 2048;
  const int idx = blockIdx.x;
  const int bh = idx & 63;
  const int b = bh >> 4, h = bh & 15;
  // balanced q-tile remap: perm = [[0,1,2,3],[7,6,5,4],[8,9,10,11],[15,14,13,12]]
  const int j = (idx >> 6) & 3;
  const int sr = idx >> 8;
  const int qt_rev = (sr >> 1) * 8 + ((sr & 1) ? (7 - j) : j);
  const int q0 = (15 - qt_rev) * 128;
  const u16* Qh = Q + (size_t)bh * S * 64;
  const u16* Kh = K + (size_t)bh * S * 64;
  const u16* Vth = Vt + (size_t)bh * 64 * S;
  const int tid = threadIdx.x, wave = tid >> 6, lane = tid & 63;
  const int fr = lane & 15, quad = lane >> 4;

  __shared__ u16 lds_k[2][2 * 64 * 32];    // dbuf [kc][kpos 64][d 32]  16 KB
  __shared__ u16 lds_vt[2][2 * 64 * 32];   // dbuf [kc][d 64][kpos 32]  16 KB
  __shared__ u16 lds_p[4][32 * 76];        // per-wave [q 32][76]       19 KB
  __shared__ float lds_bias[2][64];

  const int qb = q0 + wave * 32;  // wave's first q row
  bf16x8 qfrag[2][2];
#pragma unroll
  for (int mt = 0; mt < 2; ++mt)
#pragma unroll
    for (int kk = 0; kk < 2; ++kk)
      qfrag[mt][kk] =
          *(const bf16x8*)(Qh + (size_t)(qb + mt * 16 + fr) * 64 + kk * 32 + quad * 8);

  bf16x8 ones;
#pragma unroll
  for (int jj = 0; jj < 8; ++jj) ones[jj] = (__bf16)1.0f;

  f32x4 zero = {0.f, 0.f, 0.f, 0.f};
  f32x4 o_acc[2][4], lacc[2];
#pragma unroll
  for (int mt = 0; mt < 2; ++mt) {
    lacc[mt] = zero;
#pragma unroll
    for (int nt = 0; nt < 4; ++nt) o_acc[mt][nt] = zero;
  }

  u16* pw = lds_p[wave];
  const float NEG = -__builtin_inff();

  auto stage = [&](int k0, int bufi) {
#pragma unroll
    for (int it = 0; it < 2; ++it) {
      const int slot = it * 256 + tid;
      const int row = tid >> 2;
      const int c8 = (tid & 3) * 8;
      async_copy16(Kh + (size_t)(k0 + row) * 64 + it * 32 + c8,
                   &lds_k[bufi][slot * 8]);
      async_copy16(Vth + (size_t)row * 2048 + k0 + it * 32 + c8,
                   &lds_vt[bufi][slot * 8]);
    }
    if (tid < 64) lds_bias[bufi][tid] = pad[b * S + k0 + tid] ? -M0SHIFT : NEG;
  };

  const int kend = q0 + 64;  // last k-tile origin (inclusive)
  stage(0, 0);
  __syncthreads();  // drains vmcnt(0): tile 0 resident
  int cur = 0;

  for (int k0 = 0; k0 <= kend; k0 += 64) {
    if (k0 < kend) stage(k0 + 64, cur ^ 1);  // prefetch next tile

    if (k0 <= qb + 31) {  // wave-uniform: skip fully-masked tiles
      const u16* lk = lds_k[cur];
      const u16* lvt = lds_vt[cur];
      const float* lb = lds_bias[cur];
      const bool needMask = (k0 + 63 > qb);
#pragma unroll
      for (int nt = 0; nt < 4; ++nt) {
        f32x4 s0 = zero, s1 = zero;
#pragma unroll
        for (int kk = 0; kk < 2; ++kk) {
          bf16x8 bfrag =
              *(const bf16x8*)(lk + (kk * 64 + nt * 16 + fr) * 32 + quad * 8);
          s0 = MFMA_BF16(qfrag[0][kk], bfrag, s0);
          s1 = MFMA_BF16(qfrag[1][kk], bfrag, s1);
        }
        const float bias = lb[nt * 16 + fr];
        const int col = k0 + nt * 16 + fr;
#pragma unroll
        for (int r = 0; r < 4; ++r) {
          float v0 = s0[r] + bias;
          float v1 = s1[r] + bias;
          if (needMask) {
            if (col > qb + quad * 4 + r) v0 = NEG;
            if (col > qb + 16 + quad * 4 + r) v1 = NEG;
          }
          const float p0 = __builtin_amdgcn_exp2f(v0);
          const float p1 = __builtin_amdgcn_exp2f(v1);
          pw[(quad * 4 + r) * 76 + nt * 16 + fr] =
              (u16)(__builtin_bit_cast(u32, p0) >> 16);
          pw[(16 + quad * 4 + r) * 76 + nt * 16 + fr] =
              (u16)(__builtin_bit_cast(u32, p1) >> 16);
        }
      }
      // per-wave P bounce complete before A-frag reads (wave-private buffer)
      asm volatile("s_waitcnt lgkmcnt(0)" ::: "memory");

#pragma unroll
      for (int kk = 0; kk < 2; ++kk) {
        bf16x8 p0 = *(const bf16x8*)(pw + fr * 76 + kk * 32 + quad * 8);
        bf16x8 p1 = *(const bf16x8*)(pw + (16 + fr) * 76 + kk * 32 + quad * 8);
        lacc[0] = MFMA_BF16(p0, ones, lacc[0]);
        lacc[1] = MFMA_BF16(p1, ones, lacc[1]);
#pragma unroll
        for (int nt = 0; nt < 4; ++nt) {
          bf16x8 vf =
              *(const bf16x8*)(lvt + (kk * 64 + nt * 16 + fr) * 32 + quad * 8);
          o_acc[0][nt] = MFMA_BF16(p0, vf, o_acc[0][nt]);
          o_acc[1][nt] = MFMA_BF16(p1, vf, o_acc[1][nt]);
        }
      }
    }

    __syncthreads();  // drains vmcnt(0) (prefetch landed) + all reads of cur done
    cur ^= 1;
  }

  // epilogue: normalize, write [B][S][H*64]
#pragma unroll
  for (int mt = 0; mt < 2; ++mt)
#pragma unroll
    for (int r = 0; r < 4; ++r) {
      const int row = qb + mt * 16 + quad * 4 + r;
      const float l = lacc[mt][r];
      const float rl = (l > 0.f) ? (1.0f / l) : 0.f;
#pragma unroll
      for (int nt = 0; nt < 4; ++nt)
        O[(size_t)(b * S + row) * 1024 + h * 64 + nt * 16 + fr] =
            f2bf(o_acc[mt][nt][r] * rl);
    }
}

// ---------- kernel 3: output projection (writes fp32 to d_out) ----------

__global__ __launch_bounds__(256) void oproj_kernel(
    const u16* __restrict__ A, const u16* __restrict__ w_o, float* __restrict__ out) {
  __shared__ u16 lds[8192];
  f32x4 acc[4][4];
  const int row0 = blockIdx.y * 128;
  const int col0 = blockIdx.x * 128;
  gemm_bt_tile(A, w_o, 1024, row0, col0, lds, acc);
  const int tid = threadIdx.x;
  const int wave = tid >> 6, lane = tid & 63;
  const int fr = lane & 15, quad = lane >> 4;
  const int wm = (wave >> 1) * 64, wn = (wave & 1) * 64;
#pragma unroll
  for (int mt = 0; mt < 4; ++mt)
#pragma unroll
    for (int nt = 0; nt < 4; ++nt) {
      const int ncol = col0 + wn + nt * 16 + fr;
#pragma unroll
      for (int r = 0; r < 4; ++r) {
        const int mrow = row0 + wm + mt * 16 + quad * 4 + r;
        out[(size_t)mrow * 1024 + ncol] = acc[mt][nt][r];
      }
    }
}

// ---------- launch ----------

extern "C" void kernel_launch(void* const* d_in, const int* in_sizes, int n_in,
                              void* d_out, int out_size, void* d_ws, size_t ws_size,
                              hipStream_t stream) {
  const float* x_f = (const float*)d_in[0];     // [4][2048][1024] fp32
  const int* pad = (const int*)d_in[1];         // [4][2048] int32
  const float* wqkv_f = (const float*)d_in[2];  // [3072][1024] fp32
  const float* wo_f = (const float*)d_in[3];    // [1024][1024] fp32
  float* out = (float*)d_out;                   // [4][2048][1024] fp32

  const int NX = 4 * 2048 * 1024;
  const int NWQKV = 3072 * 1024;
  const int NWO = 1024 * 1024;
  const size_t HSZ = (size_t)4 * 16 * 2048 * 64;  // 8M elems per head-tensor

  u16* xb = (u16*)d_ws;            // 16 MB
  u16* wqkvb = xb + NX;            // 6 MB
  u16* wob = wqkvb + NWQKV;        // 2 MB
  u16* q_ws = wob + NWO;           // 16 MB  [B][H][S][64] (pre-scaled, roped)
  u16* k_ws = q_ws + HSZ;          // 16 MB  [B][H][S][64] (roped)
  u16* vt_ws = k_ws + HSZ;         // 16 MB  [B][H][64][S] (transposed)
  u16* attn_ws = vt_ws + HSZ;      // 16 MB  [B*S][D]
  float2* rope_t = (float2*)(attn_ws + HSZ);  // 512 KB [2048][32]

  dim3 blk(256);
  prep_kernel<<<dim3(12544), blk, 0, stream>>>(x_f, wqkv_f, wo_f, xb, wqkvb, wob, rope_t);
  qkv_rope_kernel<<<dim3(24, 64), blk, 0, stream>>>(xb, wqkvb, rope_t, q_ws, k_ws, vt_ws);
  flash_attn_kernel<<<dim3(1024), blk, 0, stream>>>(q_ws, k_ws, vt_ws, pad, attn_ws);
  oproj_kernel<<<dim3(8, 64), blk, 0, stream>>>(attn_ws, wob, out);
}

// Round 3
// 276.752 us; speedup vs baseline: 1.0591x; 1.0451x over previous
//
#include <hip/hip_runtime.h>

typedef unsigned short u16;
typedef unsigned int u32;
typedef __bf16 bf16x8 __attribute__((ext_vector_type(8)));
typedef float f32x4 __attribute__((ext_vector_type(4)));

#define MFMA_BF16(a, b, c) __builtin_amdgcn_mfma_f32_16x16x32_bf16((a), (b), (c), 0, 0, 0)

// log2-domain constants
#define QSCALE 0.18033688011112042f   // 0.125 * log2(e): folded into w_qkv Q-rows at prep
#define M0SHIFT 24.0f                 // fixed softmax shift (log2 domain)

#define BARRIER __builtin_amdgcn_s_barrier()
#define LGKM0                                                \
  do {                                                       \
    asm volatile("s_waitcnt lgkmcnt(0)" ::: "memory");       \
    __builtin_amdgcn_sched_barrier(0);                       \
  } while (0)
#define WAIT_VM(N) asm volatile("s_waitcnt vmcnt(" #N ")" ::: "memory")

// ---------- helpers ----------

__device__ __forceinline__ u16 f2bf(float f) {
  u32 u = __builtin_bit_cast(u32, f);
  u += 0x7fffu + ((u >> 16) & 1u);   // RNE
  return (u16)(u >> 16);
}

__device__ __forceinline__ void async_copy16(const void* g, void* l) {
  __builtin_amdgcn_global_load_lds(
      (__attribute__((address_space(1))) void*)g,
      (__attribute__((address_space(3))) void*)l, 16, 0, 0);
}

// ---------- kernel 0: fused fp32->bf16 converts + RoPE cos/sin table ----------

__global__ __launch_bounds__(256) void prep_kernel(
    const float* __restrict__ x_f, const float* __restrict__ wqkv_f,
    const float* __restrict__ wo_f, u16* __restrict__ xb,
    u16* __restrict__ wqkvb, u16* __restrict__ wob, float2* __restrict__ rope_t) {
  const int blk = blockIdx.x;
  if (blk < 12288) {
    const float* src;
    u16* dst;
    int base;
    float scale = 1.0f;
    if (blk < 8192)      { src = x_f;    dst = xb;    base = blk; }
    else if (blk < 11264){ src = wqkv_f; dst = wqkvb; base = blk - 8192;
                           if (base < 1024) scale = QSCALE; }  // Q rows
    else                 { src = wo_f;   dst = wob;   base = blk - 11264; }
    const int i = base * 1024 + threadIdx.x * 4;
    const float4 v = *(const float4*)(src + i);
    ushort4 o;
    o.x = f2bf(v.x * scale); o.y = f2bf(v.y * scale);
    o.z = f2bf(v.z * scale); o.w = f2bf(v.w * scale);
    *(ushort4*)(dst + i) = o;
  } else {
    const int idx = (blk - 12288) * 256 + threadIdx.x;  // [0, 65536)
    const int s = idx >> 5, i = idx & 31;
    const float invf = __builtin_amdgcn_exp2f(-(float)i * 0.41524101186092027f);
    float rev = (float)s * invf * 0.15915494309189535f;  // radians -> revolutions
    rev -= floorf(rev);
    rope_t[idx] = make_float2(__builtin_amdgcn_cosf(rev), __builtin_amdgcn_sinf(rev));
  }
}

// ---------- 256x128 GEMM-BT core: phase-split + counted vmcnt + XOR swizzle ---
// 512 threads = 8 waves (4M x 2N); per-wave 64x64 out = acc[4][4].
// LDS: 2 x (A[256][64] + B[128][64]) u16 = 96 KB -> 1 block/CU.
// K-tile = 64 (16 tiles at K=1024). Tile t+2 staged at end of tile t into the
// buffer whose reads just completed; vmcnt(6) (never 0) retires tile t+1's 6
// loads while t+2's 6 stay in flight -> full-tile latency cover.
// LDS swizzle: row stride 128B = bank wrap; col16 ^= (row&7) applied on the
// global SOURCE (linear gload_lds dest) and on the ds_read address (rule #21).

__device__ __forceinline__ void gemm256_bt(const u16* __restrict__ A,
                                           const u16* __restrict__ B,
                                           int row0, int col0, u16* lds,
                                           f32x4 acc[4][4]) {
  const int tid = threadIdx.x;
  const int wave = tid >> 6, lane = tid & 63;
  const int fr = lane & 15, quad = lane >> 4;
  const int wm = (wave >> 1) * 64;   // 0,64,128,192
  const int wn = (wave & 1) * 64;    // 0,64
  u16* bufA0 = lds;                  // [256][64]
  u16* bufB0 = lds + 16384;          // [128][64]
  u16* bufA1 = lds + 24576;
  u16* bufB1 = lds + 40960;

  const int l8 = lane >> 3, l7 = lane & 7;
  const int csw = (l7 ^ l8) * 8;     // pre-swizzled source col (l8 < 8)

  f32x4 zero = {0.f, 0.f, 0.f, 0.f};
#pragma unroll
  for (int mt = 0; mt < 4; ++mt)
#pragma unroll
    for (int nt = 0; nt < 4; ++nt) acc[mt][nt] = zero;

  auto stage = [&](int t) {
    u16* ba = (t & 1) ? bufA1 : bufA0;
    u16* bb = (t & 1) ? bufB1 : bufB0;
    const int k0 = t * 64;
#pragma unroll
    for (int c = 0; c < 4; ++c) {
      const int ch = c * 8 + wave;   // 0..31 -> rows [ch*8, ch*8+8)
      async_copy16(A + (size_t)(row0 + ch * 8 + l8) * 1024 + k0 + csw,
                   ba + ch * 512);
    }
#pragma unroll
    for (int c = 0; c < 2; ++c) {
      const int ch = c * 8 + wave;   // 0..15
      async_copy16(B + (size_t)(col0 + ch * 8 + l8) * 1024 + k0 + csw,
                   bb + ch * 512);
    }
  };

  // read-side swizzled column offsets (row&7 == fr&7 since wm,wn,16*t are 8-mult)
  const int f7 = fr & 7;
  const int sw0 = (quad ^ f7) * 8;         // kk = 0
  const int sw1 = ((quad + 4) ^ f7) * 8;   // kk = 1
  const int ar0 = (wm + fr) * 64, ar1 = (wm + 16 + fr) * 64;
  const int ar2 = (wm + 32 + fr) * 64, ar3 = (wm + 48 + fr) * 64;
  const int br0 = (wn + fr) * 64, br1 = (wn + 16 + fr) * 64;
  const int br2 = (wn + 32 + fr) * 64, br3 = (wn + 48 + fr) * 64;

  stage(0);
  stage(1);
  WAIT_VM(6);   // tile 0 resident (own share)
  BARRIER;      // everyone's share resident

  for (int t = 0; t < 16; ++t) {
    const u16* ba = (t & 1) ? bufA1 : bufA0;
    const u16* bb = (t & 1) ? bufB1 : bufB0;

    // ---- phase 0: read a0,a1 + b0,b1 ; MFMA quadrant mt{0,1} x nt{0,1} ----
    bf16x8 a0k0 = *(const bf16x8*)(ba + ar0 + sw0);
    bf16x8 a0k1 = *(const bf16x8*)(ba + ar0 + sw1);
    bf16x8 a1k0 = *(const bf16x8*)(ba + ar1 + sw0);
    bf16x8 a1k1 = *(const bf16x8*)(ba + ar1 + sw1);
    bf16x8 b0k0 = *(const bf16x8*)(bb + br0 + sw0);
    bf16x8 b0k1 = *(const bf16x8*)(bb + br0 + sw1);
    bf16x8 b1k0 = *(const bf16x8*)(bb + br1 + sw0);
    bf16x8 b1k1 = *(const bf16x8*)(bb + br1 + sw1);
    BARRIER;
    LGKM0;
    __builtin_amdgcn_s_setprio(1);
    acc[0][0] = MFMA_BF16(a0k0, b0k0, acc[0][0]);
    acc[0][1] = MFMA_BF16(a0k0, b1k0, acc[0][1]);
    acc[1][0] = MFMA_BF16(a1k0, b0k0, acc[1][0]);
    acc[1][1] = MFMA_BF16(a1k0, b1k0, acc[1][1]);
    acc[0][0] = MFMA_BF16(a0k1, b0k1, acc[0][0]);
    acc[0][1] = MFMA_BF16(a0k1, b1k1, acc[0][1]);
    acc[1][0] = MFMA_BF16(a1k1, b0k1, acc[1][0]);
    acc[1][1] = MFMA_BF16(a1k1, b1k1, acc[1][1]);
    __builtin_amdgcn_s_setprio(0);
    BARRIER;

    // ---- phase 1: read b2,b3 ; MFMA quadrant mt{0,1} x nt{2,3} ----
    bf16x8 b2k0 = *(const bf16x8*)(bb + br2 + sw0);
    bf16x8 b2k1 = *(const bf16x8*)(bb + br2 + sw1);
    bf16x8 b3k0 = *(const bf16x8*)(bb + br3 + sw0);
    bf16x8 b3k1 = *(const bf16x8*)(bb + br3 + sw1);
    BARRIER;
    LGKM0;
    __builtin_amdgcn_s_setprio(1);
    acc[0][2] = MFMA_BF16(a0k0, b2k0, acc[0][2]);
    acc[0][3] = MFMA_BF16(a0k0, b3k0, acc[0][3]);
    acc[1][2] = MFMA_BF16(a1k0, b2k0, acc[1][2]);
    acc[1][3] = MFMA_BF16(a1k0, b3k0, acc[1][3]);
    acc[0][2] = MFMA_BF16(a0k1, b2k1, acc[0][2]);
    acc[0][3] = MFMA_BF16(a0k1, b3k1, acc[0][3]);
    acc[1][2] = MFMA_BF16(a1k1, b2k1, acc[1][2]);
    acc[1][3] = MFMA_BF16(a1k1, b3k1, acc[1][3]);
    __builtin_amdgcn_s_setprio(0);
    BARRIER;

    // ---- phase 2: read a2,a3 ; MFMA quadrants mt{2,3} x nt{0..3} ----
    bf16x8 a2k0 = *(const bf16x8*)(ba + ar2 + sw0);
    bf16x8 a2k1 = *(const bf16x8*)(ba + ar2 + sw1);
    bf16x8 a3k0 = *(const bf16x8*)(ba + ar3 + sw0);
    bf16x8 a3k1 = *(const bf16x8*)(ba + ar3 + sw1);
    BARRIER;
    LGKM0;
    __builtin_amdgcn_s_setprio(1);
    acc[2][0] = MFMA_BF16(a2k0, b0k0, acc[2][0]);
    acc[2][1] = MFMA_BF16(a2k0, b1k0, acc[2][1]);
    acc[3][0] = MFMA_BF16(a3k0, b0k0, acc[3][0]);
    acc[3][1] = MFMA_BF16(a3k0, b1k0, acc[3][1]);
    acc[2][0] = MFMA_BF16(a2k1, b0k1, acc[2][0]);
    acc[2][1] = MFMA_BF16(a2k1, b1k1, acc[2][1]);
    acc[3][0] = MFMA_BF16(a3k1, b0k1, acc[3][0]);
    acc[3][1] = MFMA_BF16(a3k1, b1k1, acc[3][1]);
    acc[2][2] = MFMA_BF16(a2k0, b2k0, acc[2][2]);
    acc[2][3] = MFMA_BF16(a2k0, b3k0, acc[2][3]);
    acc[3][2] = MFMA_BF16(a3k0, b2k0, acc[3][2]);
    acc[3][3] = MFMA_BF16(a3k0, b3k0, acc[3][3]);
    acc[2][2] = MFMA_BF16(a2k1, b2k1, acc[2][2]);
    acc[2][3] = MFMA_BF16(a2k1, b3k1, acc[2][3]);
    acc[3][2] = MFMA_BF16(a3k1, b2k1, acc[3][2]);
    acc[3][3] = MFMA_BF16(a3k1, b3k1, acc[3][3]);
    __builtin_amdgcn_s_setprio(0);

    // ---- tile end: all reads of buf[t&1] done after this barrier ----
    BARRIER;
    if (t + 2 < 16) {
      stage(t + 2);          // into buf[t&1] (reads just completed)
      WAIT_VM(6);            // tile t+1 resident; t+2's 6 loads in flight
    } else if (t + 2 == 16) {
      WAIT_VM(0);            // last prefetch drains (one-time epilogue cost)
    }
    BARRIER;
  }
}

// ---------- kernel 1: QKV projection + RoPE, coalesced LDS-bounce epilogue ----
// 256x128 tiles: grid (24, 32) = 768 blocks = 3 exact rounds of 256 CUs.

__global__ __launch_bounds__(512, 2) void qkv_rope_kernel(
    const u16* __restrict__ x, const u16* __restrict__ w_qkv,
    const float2* __restrict__ rope_t,
    u16* __restrict__ q_ws, u16* __restrict__ k_ws, u16* __restrict__ vt_ws) {
  __shared__ u16 lds[49152];  // 96 KB: gemm dbuf; epilogue reuses it
  f32x4 acc[4][4];
  const int row0 = blockIdx.y * 256;  // M = 8192
  const int col0 = blockIdx.x * 128;  // N = 3072
  gemm256_bt(x, w_qkv, row0, col0, lds, acc);

  const int tid = threadIdx.x;
  const int wave = tid >> 6, lane = tid & 63;
  const int fr = lane & 15, quad = lane >> 4;
  const int wm = (wave >> 1) * 64, wn = (wave & 1) * 64;
  const int region = col0 >> 10;      // 0=Q 1=K 2=V (block-uniform; 1024%128==0)
  const int f0 = col0 & 1023;
  const int s0r = row0 & 2047;
  const int bb = row0 >> 11;
  const int h0 = f0 >> 6;             // block covers heads h0, h0+1

  // gemm256_bt's final BARRIER: all waves done with mainloop LDS

  if (region < 2) {
    // rotate in registers, stage [m 256][n 128] (stride 136)
#pragma unroll
    for (int mt = 0; mt < 4; ++mt) {
#pragma unroll
      for (int nt = 0; nt < 4; ++nt) {
        const int n = wn + nt * 16 + fr;
        const int d = n & 63;  // col0/wn are 64-aligned
#pragma unroll
        for (int r = 0; r < 4; ++r) {
          const int m = wm + mt * 16 + quad * 4 + r;
          const float own = acc[mt][nt][r];
          const float part = __shfl_xor(own, 1);
          const int s = s0r + m;
          const float2 cssn = rope_t[s * 32 + (d >> 1)];
          const float val = (d & 1) ? (part * cssn.y + own * cssn.x)
                                    : (own * cssn.x - part * cssn.y);
          lds[m * 136 + n] = f2bf(val);
        }
      }
    }
    __syncthreads();
    u16* dst = (region == 0) ? q_ws : k_ws;
#pragma unroll
    for (int j = 0; j < 8; ++j) {
      const int idx2 = j * 512 + tid;       // 0..4095
      const int m = idx2 >> 4;              // 0..255
      const int rem = idx2 & 15;
      const int hf = rem >> 3;              // head half (0/1)
      const int c8 = (rem & 7) * 8;
      const uint4 v = *(const uint4*)(lds + m * 136 + hf * 64 + c8);
      *(uint4*)(dst + ((size_t)(bb * 16 + h0 + hf) * 2048 + s0r + m) * 64 + c8) = v;
    }
  } else {
    // stage transposed [n 128][m 256] (stride 264)
#pragma unroll
    for (int mt = 0; mt < 4; ++mt)
#pragma unroll
      for (int nt = 0; nt < 4; ++nt) {
        const int n = wn + nt * 16 + fr;
#pragma unroll
        for (int r = 0; r < 4; ++r) {
          const int m = wm + mt * 16 + quad * 4 + r;
          lds[n * 264 + m] = f2bf(acc[mt][nt][r]);
        }
      }
    __syncthreads();
#pragma unroll
    for (int j = 0; j < 8; ++j) {
      const int idx2 = j * 512 + tid;       // 0..4095
      const int n = idx2 >> 5;              // 0..127
      const int mc = (idx2 & 31) * 8;       // 0..248
      const int h = h0 + (n >> 6);
      const int d = n & 63;
      const uint4 v = *(const uint4*)(lds + n * 264 + mc);
      *(uint4*)(vt_ws + ((size_t)(bb * 16 + h) * 64 + d) * 2048 + s0r + mc) = v;
    }
  }
}

// ---------- kernel 2: causal flash attention (fixed-shift log2 softmax) ------
// grid 1024: bh in low 6 bits; balanced q-tile permutation; K/V LDS dbuf.

__global__ __launch_bounds__(256, 3) void flash_attn_kernel(
    const u16* __restrict__ Q, const u16* __restrict__ K, const u16* __restrict__ Vt,
    const int* __restrict__ pad, u16* __restrict__ O) {
  const int S = 2048;
  const int idx = blockIdx.x;
  const int bh = idx & 63;
  const int b = bh >> 4, h = bh & 15;
  // balanced q-tile remap: perm = [[0,1,2,3],[7,6,5,4],[8,9,10,11],[15,14,13,12]]
  const int j = (idx >> 6) & 3;
  const int sr = idx >> 8;
  const int qt_rev = (sr >> 1) * 8 + ((sr & 1) ? (7 - j) : j);
  const int q0 = (15 - qt_rev) * 128;
  const u16* Qh = Q + (size_t)bh * S * 64;
  const u16* Kh = K + (size_t)bh * S * 64;
  const u16* Vth = Vt + (size_t)bh * 64 * S;
  const int tid = threadIdx.x, wave = tid >> 6, lane = tid & 63;
  const int fr = lane & 15, quad = lane >> 4;

  __shared__ u16 lds_k[2][2 * 64 * 32];    // dbuf [kc][kpos 64][d 32]  16 KB
  __shared__ u16 lds_vt[2][2 * 64 * 32];   // dbuf [kc][d 64][kpos 32]  16 KB
  __shared__ u16 lds_p[4][32 * 76];        // per-wave [q 32][76]       19 KB
  __shared__ float lds_bias[2][64];

  const int qb = q0 + wave * 32;  // wave's first q row
  bf16x8 qfrag[2][2];
#pragma unroll
  for (int mt = 0; mt < 2; ++mt)
#pragma unroll
    for (int kk = 0; kk < 2; ++kk)
      qfrag[mt][kk] =
          *(const bf16x8*)(Qh + (size_t)(qb + mt * 16 + fr) * 64 + kk * 32 + quad * 8);

  bf16x8 ones;
#pragma unroll
  for (int jj = 0; jj < 8; ++jj) ones[jj] = (__bf16)1.0f;

  f32x4 zero = {0.f, 0.f, 0.f, 0.f};
  f32x4 o_acc[2][4], lacc[2];
#pragma unroll
  for (int mt = 0; mt < 2; ++mt) {
    lacc[mt] = zero;
#pragma unroll
    for (int nt = 0; nt < 4; ++nt) o_acc[mt][nt] = zero;
  }

  u16* pw = lds_p[wave];
  const float NEG = -__builtin_inff();

  auto stage = [&](int k0, int bufi) {
#pragma unroll
    for (int it = 0; it < 2; ++it) {
      const int slot = it * 256 + tid;
      const int row = tid >> 2;
      const int c8 = (tid & 3) * 8;
      async_copy16(Kh + (size_t)(k0 + row) * 64 + it * 32 + c8,
                   &lds_k[bufi][slot * 8]);
      async_copy16(Vth + (size_t)row * 2048 + k0 + it * 32 + c8,
                   &lds_vt[bufi][slot * 8]);
    }
    if (tid < 64) lds_bias[bufi][tid] = pad[b * S + k0 + tid] ? -M0SHIFT : NEG;
  };

  const int kend = q0 + 64;  // last k-tile origin (inclusive)
  stage(0, 0);
  __syncthreads();  // drains vmcnt(0): tile 0 resident
  int cur = 0;

  for (int k0 = 0; k0 <= kend; k0 += 64) {
    if (k0 < kend) stage(k0 + 64, cur ^ 1);  // prefetch next tile

    if (k0 <= qb + 31) {  // wave-uniform: skip fully-masked tiles
      const u16* lk = lds_k[cur];
      const u16* lvt = lds_vt[cur];
      const float* lb = lds_bias[cur];
      const bool needMask = (k0 + 63 > qb);
#pragma unroll
      for (int nt = 0; nt < 4; ++nt) {
        f32x4 s0 = zero, s1 = zero;
#pragma unroll
        for (int kk = 0; kk < 2; ++kk) {
          bf16x8 bfrag =
              *(const bf16x8*)(lk + (kk * 64 + nt * 16 + fr) * 32 + quad * 8);
          s0 = MFMA_BF16(qfrag[0][kk], bfrag, s0);
          s1 = MFMA_BF16(qfrag[1][kk], bfrag, s1);
        }
        const float bias = lb[nt * 16 + fr];
        const int col = k0 + nt * 16 + fr;
#pragma unroll
        for (int r = 0; r < 4; ++r) {
          float v0 = s0[r] + bias;
          float v1 = s1[r] + bias;
          if (needMask) {
            if (col > qb + quad * 4 + r) v0 = NEG;
            if (col > qb + 16 + quad * 4 + r) v1 = NEG;
          }
          const float p0 = __builtin_amdgcn_exp2f(v0);
          const float p1 = __builtin_amdgcn_exp2f(v1);
          pw[(quad * 4 + r) * 76 + nt * 16 + fr] =
              (u16)(__builtin_bit_cast(u32, p0) >> 16);
          pw[(16 + quad * 4 + r) * 76 + nt * 16 + fr] =
              (u16)(__builtin_bit_cast(u32, p1) >> 16);
        }
      }
      // per-wave P bounce complete before A-frag reads (wave-private buffer)
      asm volatile("s_waitcnt lgkmcnt(0)" ::: "memory");

#pragma unroll
      for (int kk = 0; kk < 2; ++kk) {
        bf16x8 p0 = *(const bf16x8*)(pw + fr * 76 + kk * 32 + quad * 8);
        bf16x8 p1 = *(const bf16x8*)(pw + (16 + fr) * 76 + kk * 32 + quad * 8);
        lacc[0] = MFMA_BF16(p0, ones, lacc[0]);
        lacc[1] = MFMA_BF16(p1, ones, lacc[1]);
#pragma unroll
        for (int nt = 0; nt < 4; ++nt) {
          bf16x8 vf =
              *(const bf16x8*)(lvt + (kk * 64 + nt * 16 + fr) * 32 + quad * 8);
          o_acc[0][nt] = MFMA_BF16(p0, vf, o_acc[0][nt]);
          o_acc[1][nt] = MFMA_BF16(p1, vf, o_acc[1][nt]);
        }
      }
    }

    __syncthreads();  // drains vmcnt(0) (prefetch landed) + all reads of cur done
    cur ^= 1;
  }

  // epilogue: normalize, write [B][S][H*64]
#pragma unroll
  for (int mt = 0; mt < 2; ++mt)
#pragma unroll
    for (int r = 0; r < 4; ++r) {
      const int row = qb + mt * 16 + quad * 4 + r;
      const float l = lacc[mt][r];
      const float rl = (l > 0.f) ? (1.0f / l) : 0.f;
#pragma unroll
      for (int nt = 0; nt < 4; ++nt)
        O[(size_t)(b * S + row) * 1024 + h * 64 + nt * 16 + fr] =
            f2bf(o_acc[mt][nt][r] * rl);
    }
}

// ---------- kernel 3: output projection (writes fp32 to d_out) ----------
// 256x128 tiles: grid (8, 32) = 256 blocks = 1 exact round.

__global__ __launch_bounds__(512, 2) void oproj_kernel(
    const u16* __restrict__ A, const u16* __restrict__ w_o, float* __restrict__ out) {
  __shared__ u16 lds[49152];
  f32x4 acc[4][4];
  const int row0 = blockIdx.y * 256;
  const int col0 = blockIdx.x * 128;
  gemm256_bt(A, w_o, row0, col0, lds, acc);
  const int tid = threadIdx.x;
  const int wave = tid >> 6, lane = tid & 63;
  const int fr = lane & 15, quad = lane >> 4;
  const int wm = (wave >> 1) * 64, wn = (wave & 1) * 64;
#pragma unroll
  for (int mt = 0; mt < 4; ++mt)
#pragma unroll
    for (int nt = 0; nt < 4; ++nt) {
      const int ncol = col0 + wn + nt * 16 + fr;
#pragma unroll
      for (int r = 0; r < 4; ++r) {
        const int mrow = row0 + wm + mt * 16 + quad * 4 + r;
        out[(size_t)mrow * 1024 + ncol] = acc[mt][nt][r];
      }
    }
}

// ---------- launch ----------

extern "C" void kernel_launch(void* const* d_in, const int* in_sizes, int n_in,
                              void* d_out, int out_size, void* d_ws, size_t ws_size,
                              hipStream_t stream) {
  const float* x_f = (const float*)d_in[0];     // [4][2048][1024] fp32
  const int* pad = (const int*)d_in[1];         // [4][2048] int32
  const float* wqkv_f = (const float*)d_in[2];  // [3072][1024] fp32
  const float* wo_f = (const float*)d_in[3];    // [1024][1024] fp32
  float* out = (float*)d_out;                   // [4][2048][1024] fp32

  const int NX = 4 * 2048 * 1024;
  const int NWQKV = 3072 * 1024;
  const int NWO = 1024 * 1024;
  const size_t HSZ = (size_t)4 * 16 * 2048 * 64;  // 8M elems per head-tensor

  u16* xb = (u16*)d_ws;            // 16 MB
  u16* wqkvb = xb + NX;            // 6 MB
  u16* wob = wqkvb + NWQKV;        // 2 MB
  u16* q_ws = wob + NWO;           // 16 MB  [B][H][S][64] (pre-scaled, roped)
  u16* k_ws = q_ws + HSZ;          // 16 MB  [B][H][S][64] (roped)
  u16* vt_ws = k_ws + HSZ;         // 16 MB  [B][H][64][S] (transposed)
  u16* attn_ws = vt_ws + HSZ;      // 16 MB  [B*S][D]
  float2* rope_t = (float2*)(attn_ws + HSZ);  // 512 KB [2048][32]

  prep_kernel<<<dim3(12544), dim3(256), 0, stream>>>(x_f, wqkv_f, wo_f, xb, wqkvb,
                                                     wob, rope_t);
  qkv_rope_kernel<<<dim3(24, 32), dim3(512), 0, stream>>>(xb, wqkvb, rope_t, q_ws,
                                                          k_ws, vt_ws);
  flash_attn_kernel<<<dim3(1024), dim3(256), 0, stream>>>(q_ws, k_ws, vt_ws, pad,
                                                          attn_ws);
  oproj_kernel<<<dim3(8, 32), dim3(512), 0, stream>>>(attn_ws, wob, out);
}

// Round 4
// 251.884 us; speedup vs baseline: 1.1637x; 1.0987x over previous
//
#include <hip/hip_runtime.h>

typedef unsigned short u16;
typedef unsigned int u32;
typedef __bf16 bf16x8 __attribute__((ext_vector_type(8)));
typedef float f32x4 __attribute__((ext_vector_type(4)));
typedef float f32x16 __attribute__((ext_vector_type(16)));
typedef u32 u32x4 __attribute__((ext_vector_type(4)));

#define MFMA_BF16(a, b, c) __builtin_amdgcn_mfma_f32_16x16x32_bf16((a), (b), (c), 0, 0, 0)
#define MFMA32(a, b, c) __builtin_amdgcn_mfma_f32_32x32x16_bf16((a), (b), (c), 0, 0, 0)

// log2-domain constant: 0.125 * log2(e), folded into w_qkv Q-rows at prep
#define QSCALE 0.18033688011112042f

#define BARRIER __builtin_amdgcn_s_barrier()
#define LGKM0                                                \
  do {                                                       \
    asm volatile("s_waitcnt lgkmcnt(0)" ::: "memory");       \
    __builtin_amdgcn_sched_barrier(0);                       \
  } while (0)
#define WAIT_VM(N) asm volatile("s_waitcnt vmcnt(" #N ")" ::: "memory")

// ---------- helpers ----------

__device__ __forceinline__ u16 f2bf(float f) {
  u32 u = __builtin_bit_cast(u32, f);
  u += 0x7fffu + ((u >> 16) & 1u);   // RNE
  return (u16)(u >> 16);
}

__device__ __forceinline__ void async_copy16(const void* g, void* l) {
  __builtin_amdgcn_global_load_lds(
      (__attribute__((address_space(1))) void*)g,
      (__attribute__((address_space(3))) void*)l, 16, 0, 0);
}

__device__ __forceinline__ u32 cvt_pk_bf16(float lo, float hi) {
  u32 d;
  asm("v_cvt_pk_bf16_f32 %0, %1, %2" : "=v"(d) : "v"(lo), "v"(hi));
  return d;
}

__device__ __forceinline__ void swap32(u32& a, u32& b) {
  asm("v_permlane32_swap_b32 %0, %1" : "+v"(a), "+v"(b));
}

// ---------- kernel 0: fused fp32->bf16 converts + RoPE cos/sin table ----------

__global__ __launch_bounds__(256) void prep_kernel(
    const float* __restrict__ x_f, const float* __restrict__ wqkv_f,
    const float* __restrict__ wo_f, u16* __restrict__ xb,
    u16* __restrict__ wqkvb, u16* __restrict__ wob, float2* __restrict__ rope_t) {
  const int blk = blockIdx.x;
  if (blk < 12288) {
    const float* src;
    u16* dst;
    int base;
    float scale = 1.0f;
    if (blk < 8192)      { src = x_f;    dst = xb;    base = blk; }
    else if (blk < 11264){ src = wqkv_f; dst = wqkvb; base = blk - 8192;
                           if (base < 1024) scale = QSCALE; }  // Q rows
    else                 { src = wo_f;   dst = wob;   base = blk - 11264; }
    const int i = base * 1024 + threadIdx.x * 4;
    const float4 v = *(const float4*)(src + i);
    ushort4 o;
    o.x = f2bf(v.x * scale); o.y = f2bf(v.y * scale);
    o.z = f2bf(v.z * scale); o.w = f2bf(v.w * scale);
    *(ushort4*)(dst + i) = o;
  } else {
    const int idx = (blk - 12288) * 256 + threadIdx.x;  // [0, 65536)
    const int s = idx >> 5, i = idx & 31;
    const float invf = __builtin_amdgcn_exp2f(-(float)i * 0.41524101186092027f);
    float rev = (float)s * invf * 0.15915494309189535f;  // radians -> revolutions
    rev -= floorf(rev);
    rope_t[idx] = make_float2(__builtin_amdgcn_cosf(rev), __builtin_amdgcn_sinf(rev));
  }
}

// ---------- 256x128 GEMM-BT core: phase-split + counted vmcnt + XOR swizzle ---

__device__ __forceinline__ void gemm256_bt(const u16* __restrict__ A,
                                           const u16* __restrict__ B,
                                           int row0, int col0, u16* lds,
                                           f32x4 acc[4][4]) {
  const int tid = threadIdx.x;
  const int wave = tid >> 6, lane = tid & 63;
  const int fr = lane & 15, quad = lane >> 4;
  const int wm = (wave >> 1) * 64;   // 0,64,128,192
  const int wn = (wave & 1) * 64;    // 0,64
  u16* bufA0 = lds;                  // [256][64]
  u16* bufB0 = lds + 16384;          // [128][64]
  u16* bufA1 = lds + 24576;
  u16* bufB1 = lds + 40960;

  const int l8 = lane >> 3, l7 = lane & 7;
  const int csw = (l7 ^ l8) * 8;     // pre-swizzled source col (l8 < 8)

  f32x4 zero = {0.f, 0.f, 0.f, 0.f};
#pragma unroll
  for (int mt = 0; mt < 4; ++mt)
#pragma unroll
    for (int nt = 0; nt < 4; ++nt) acc[mt][nt] = zero;

  auto stage = [&](int t) {
    u16* ba = (t & 1) ? bufA1 : bufA0;
    u16* bb = (t & 1) ? bufB1 : bufB0;
    const int k0 = t * 64;
#pragma unroll
    for (int c = 0; c < 4; ++c) {
      const int ch = c * 8 + wave;   // 0..31 -> rows [ch*8, ch*8+8)
      async_copy16(A + (size_t)(row0 + ch * 8 + l8) * 1024 + k0 + csw,
                   ba + ch * 512);
    }
#pragma unroll
    for (int c = 0; c < 2; ++c) {
      const int ch = c * 8 + wave;   // 0..15
      async_copy16(B + (size_t)(col0 + ch * 8 + l8) * 1024 + k0 + csw,
                   bb + ch * 512);
    }
  };

  const int f7 = fr & 7;
  const int sw0 = (quad ^ f7) * 8;         // kk = 0
  const int sw1 = ((quad + 4) ^ f7) * 8;   // kk = 1
  const int ar0 = (wm + fr) * 64, ar1 = (wm + 16 + fr) * 64;
  const int ar2 = (wm + 32 + fr) * 64, ar3 = (wm + 48 + fr) * 64;
  const int br0 = (wn + fr) * 64, br1 = (wn + 16 + fr) * 64;
  const int br2 = (wn + 32 + fr) * 64, br3 = (wn + 48 + fr) * 64;

  stage(0);
  stage(1);
  WAIT_VM(6);   // tile 0 resident (own share)
  BARRIER;      // everyone's share resident

  for (int t = 0; t < 16; ++t) {
    const u16* ba = (t & 1) ? bufA1 : bufA0;
    const u16* bb = (t & 1) ? bufB1 : bufB0;

    // ---- phase 0: read a0,a1 + b0,b1 ; MFMA quadrant mt{0,1} x nt{0,1} ----
    bf16x8 a0k0 = *(const bf16x8*)(ba + ar0 + sw0);
    bf16x8 a0k1 = *(const bf16x8*)(ba + ar0 + sw1);
    bf16x8 a1k0 = *(const bf16x8*)(ba + ar1 + sw0);
    bf16x8 a1k1 = *(const bf16x8*)(ba + ar1 + sw1);
    bf16x8 b0k0 = *(const bf16x8*)(bb + br0 + sw0);
    bf16x8 b0k1 = *(const bf16x8*)(bb + br0 + sw1);
    bf16x8 b1k0 = *(const bf16x8*)(bb + br1 + sw0);
    bf16x8 b1k1 = *(const bf16x8*)(bb + br1 + sw1);
    BARRIER;
    LGKM0;
    __builtin_amdgcn_s_setprio(1);
    acc[0][0] = MFMA_BF16(a0k0, b0k0, acc[0][0]);
    acc[0][1] = MFMA_BF16(a0k0, b1k0, acc[0][1]);
    acc[1][0] = MFMA_BF16(a1k0, b0k0, acc[1][0]);
    acc[1][1] = MFMA_BF16(a1k0, b1k0, acc[1][1]);
    acc[0][0] = MFMA_BF16(a0k1, b0k1, acc[0][0]);
    acc[0][1] = MFMA_BF16(a0k1, b1k1, acc[0][1]);
    acc[1][0] = MFMA_BF16(a1k1, b0k1, acc[1][0]);
    acc[1][1] = MFMA_BF16(a1k1, b1k1, acc[1][1]);
    __builtin_amdgcn_s_setprio(0);
    BARRIER;

    // ---- phase 1: read b2,b3 ; MFMA quadrant mt{0,1} x nt{2,3} ----
    bf16x8 b2k0 = *(const bf16x8*)(bb + br2 + sw0);
    bf16x8 b2k1 = *(const bf16x8*)(bb + br2 + sw1);
    bf16x8 b3k0 = *(const bf16x8*)(bb + br3 + sw0);
    bf16x8 b3k1 = *(const bf16x8*)(bb + br3 + sw1);
    BARRIER;
    LGKM0;
    __builtin_amdgcn_s_setprio(1);
    acc[0][2] = MFMA_BF16(a0k0, b2k0, acc[0][2]);
    acc[0][3] = MFMA_BF16(a0k0, b3k0, acc[0][3]);
    acc[1][2] = MFMA_BF16(a1k0, b2k0, acc[1][2]);
    acc[1][3] = MFMA_BF16(a1k0, b3k0, acc[1][3]);
    acc[0][2] = MFMA_BF16(a0k1, b2k1, acc[0][2]);
    acc[0][3] = MFMA_BF16(a0k1, b3k1, acc[0][3]);
    acc[1][2] = MFMA_BF16(a1k1, b2k1, acc[1][2]);
    acc[1][3] = MFMA_BF16(a1k1, b3k1, acc[1][3]);
    __builtin_amdgcn_s_setprio(0);
    BARRIER;

    // ---- phase 2: read a2,a3 ; MFMA quadrants mt{2,3} x nt{0..3} ----
    bf16x8 a2k0 = *(const bf16x8*)(ba + ar2 + sw0);
    bf16x8 a2k1 = *(const bf16x8*)(ba + ar2 + sw1);
    bf16x8 a3k0 = *(const bf16x8*)(ba + ar3 + sw0);
    bf16x8 a3k1 = *(const bf16x8*)(ba + ar3 + sw1);
    BARRIER;
    LGKM0;
    __builtin_amdgcn_s_setprio(1);
    acc[2][0] = MFMA_BF16(a2k0, b0k0, acc[2][0]);
    acc[2][1] = MFMA_BF16(a2k0, b1k0, acc[2][1]);
    acc[3][0] = MFMA_BF16(a3k0, b0k0, acc[3][0]);
    acc[3][1] = MFMA_BF16(a3k0, b1k0, acc[3][1]);
    acc[2][0] = MFMA_BF16(a2k1, b0k1, acc[2][0]);
    acc[2][1] = MFMA_BF16(a2k1, b1k1, acc[2][1]);
    acc[3][0] = MFMA_BF16(a3k1, b0k1, acc[3][0]);
    acc[3][1] = MFMA_BF16(a3k1, b1k1, acc[3][1]);
    acc[2][2] = MFMA_BF16(a2k0, b2k0, acc[2][2]);
    acc[2][3] = MFMA_BF16(a2k0, b3k0, acc[2][3]);
    acc[3][2] = MFMA_BF16(a3k0, b2k0, acc[3][2]);
    acc[3][3] = MFMA_BF16(a3k0, b3k0, acc[3][3]);
    acc[2][2] = MFMA_BF16(a2k1, b2k1, acc[2][2]);
    acc[2][3] = MFMA_BF16(a2k1, b3k1, acc[2][3]);
    acc[3][2] = MFMA_BF16(a3k1, b2k1, acc[3][2]);
    acc[3][3] = MFMA_BF16(a3k1, b3k1, acc[3][3]);
    __builtin_amdgcn_s_setprio(0);

    // ---- tile end: all reads of buf[t&1] done after this barrier ----
    BARRIER;
    if (t + 2 < 16) {
      stage(t + 2);          // into buf[t&1] (reads just completed)
      WAIT_VM(6);            // tile t+1 resident; t+2's 6 loads in flight
    } else if (t + 2 == 16) {
      WAIT_VM(0);            // last prefetch drains (one-time epilogue cost)
    }
    BARRIER;
  }
}

// ---------- kernel 1: QKV projection + RoPE, coalesced LDS-bounce epilogue ----

__global__ __launch_bounds__(512, 2) void qkv_rope_kernel(
    const u16* __restrict__ x, const u16* __restrict__ w_qkv,
    const float2* __restrict__ rope_t,
    u16* __restrict__ q_ws, u16* __restrict__ k_ws, u16* __restrict__ vt_ws) {
  __shared__ u16 lds[49152];  // 96 KB: gemm dbuf; epilogue reuses it
  f32x4 acc[4][4];
  const int row0 = blockIdx.y * 256;  // M = 8192
  const int col0 = blockIdx.x * 128;  // N = 3072
  gemm256_bt(x, w_qkv, row0, col0, lds, acc);

  const int tid = threadIdx.x;
  const int wave = tid >> 6, lane = tid & 63;
  const int fr = lane & 15, quad = lane >> 4;
  const int wm = (wave >> 1) * 64, wn = (wave & 1) * 64;
  const int region = col0 >> 10;      // 0=Q 1=K 2=V (block-uniform; 1024%128==0)
  const int f0 = col0 & 1023;
  const int s0r = row0 & 2047;
  const int bb = row0 >> 11;
  const int h0 = f0 >> 6;             // block covers heads h0, h0+1

  if (region < 2) {
    // rotate in registers, stage [m 256][n 128] (stride 136)
#pragma unroll
    for (int mt = 0; mt < 4; ++mt) {
#pragma unroll
      for (int nt = 0; nt < 4; ++nt) {
        const int n = wn + nt * 16 + fr;
        const int d = n & 63;  // col0/wn are 64-aligned
#pragma unroll
        for (int r = 0; r < 4; ++r) {
          const int m = wm + mt * 16 + quad * 4 + r;
          const float own = acc[mt][nt][r];
          const float part = __shfl_xor(own, 1);
          const int s = s0r + m;
          const float2 cssn = rope_t[s * 32 + (d >> 1)];
          const float val = (d & 1) ? (part * cssn.y + own * cssn.x)
                                    : (own * cssn.x - part * cssn.y);
          lds[m * 136 + n] = f2bf(val);
        }
      }
    }
    __syncthreads();
    u16* dst = (region == 0) ? q_ws : k_ws;
#pragma unroll
    for (int j = 0; j < 8; ++j) {
      const int idx2 = j * 512 + tid;       // 0..4095
      const int m = idx2 >> 4;              // 0..255
      const int rem = idx2 & 15;
      const int hf = rem >> 3;              // head half (0/1)
      const int c8 = (rem & 7) * 8;
      const uint4 v = *(const uint4*)(lds + m * 136 + hf * 64 + c8);
      *(uint4*)(dst + ((size_t)(bb * 16 + h0 + hf) * 2048 + s0r + m) * 64 + c8) = v;
    }
  } else {
    // stage transposed [n 128][m 256] (stride 264)
#pragma unroll
    for (int mt = 0; mt < 4; ++mt)
#pragma unroll
      for (int nt = 0; nt < 4; ++nt) {
        const int n = wn + nt * 16 + fr;
#pragma unroll
        for (int r = 0; r < 4; ++r) {
          const int m = wm + mt * 16 + quad * 4 + r;
          lds[n * 264 + m] = f2bf(acc[mt][nt][r]);
        }
      }
    __syncthreads();
#pragma unroll
    for (int j = 0; j < 8; ++j) {
      const int idx2 = j * 512 + tid;       // 0..4095
      const int n = idx2 >> 5;              // 0..127
      const int mc = (idx2 & 31) * 8;       // 0..248
      const int h = h0 + (n >> 6);
      const int d = n & 63;
      const uint4 v = *(const uint4*)(lds + n * 264 + mc);
      *(uint4*)(vt_ws + ((size_t)(bb * 16 + h) * 64 + d) * 2048 + s0r + mc) = v;
    }
  }
}

// ---------- kernel 2: causal flash attention, swapped-QK 32x32 in-reg softmax -
// grid 1024: bh in low 6 bits; balanced q-tile permutation (r1); K/V dbuf (r1).
// mfma(K,Q): lane owns q-col (lane&31), kpos reg-mapped -> softmax in registers
// (exp2 only; no fixed shift -- uniform scale cancels in O/l). P->bf16 via
// v_cvt_pk_bf16_f32 + v_permlane32_swap_b32 feeds PV A-operand directly (no
// P LDS bounce). l via MFMA vs ones-frag. K/Vt LDS [64][64] XOR-swizzled
// (granule ^= row&7) as inverse-swizzled global source + swizzled ds_read.
// Padding: per-tile all-ones ballot fast path; bias {0,-inf} slow path.
// LDS 33 KB; VGPR-bound 3 blocks/CU.

__global__ __launch_bounds__(256, 3) void flash_attn_kernel(
    const u16* __restrict__ Q, const u16* __restrict__ K, const u16* __restrict__ Vt,
    const int* __restrict__ pad, u16* __restrict__ O) {
  const int S = 2048;
  const int idx = blockIdx.x;
  const int bh = idx & 63;
  const int b = bh >> 4, h = bh & 15;
  // balanced q-tile remap: perm = [[0,1,2,3],[7,6,5,4],[8,9,10,11],[15,14,13,12]]
  const int j = (idx >> 6) & 3;
  const int sr = idx >> 8;
  const int qt_rev = (sr >> 1) * 8 + ((sr & 1) ? (7 - j) : j);
  const int q0 = (15 - qt_rev) * 128;
  const u16* Qh = Q + (size_t)bh * S * 64;
  const u16* Kh = K + (size_t)bh * S * 64;
  const u16* Vth = Vt + (size_t)bh * 64 * S;
  const int tid = threadIdx.x, wave = tid >> 6, lane = tid & 63;
  const int l31 = lane & 31, hi = lane >> 5, l7 = lane & 7;

  __shared__ u16 lds_k[2][64 * 64];    // dbuf [kpos 64][d 64] swizzled  16 KB
  __shared__ u16 lds_vt[2][64 * 64];   // dbuf [d 64][kpos 64] swizzled  16 KB
  __shared__ float lds_biasf[2][64];   // {0, -inf} per kpos             512 B

  const int qb = q0 + wave * 32;  // wave's first q row

  // Q as B-operand: lane holds Q[qb + l31][d = c*16 + hi*8 + 0..7]
  bf16x8 qfrag[4];
#pragma unroll
  for (int c = 0; c < 4; ++c)
    qfrag[c] = *(const bf16x8*)(Qh + (size_t)(qb + l31) * 64 + c * 16 + hi * 8);

  bf16x8 ones;
#pragma unroll
  for (int jj = 0; jj < 8; ++jj) ones[jj] = (__bf16)1.0f;

  f32x16 o_acc0, o_acc1, lacc;
#pragma unroll
  for (int r = 0; r < 16; ++r) { o_acc0[r] = 0.f; o_acc1[r] = 0.f; lacc[r] = 0.f; }

  const float NEG = -__builtin_inff();
  int pv0 = 1, pv1 = 1;

  auto stage = [&](int k0, int bufi) {
#pragma unroll
    for (int it = 0; it < 2; ++it) {
      const int slot = it * 256 + tid;   // 0..511
      const int row = slot >> 3;         // 0..63
      const int g = slot & 7;
      const int gs = (g ^ (row & 7)) * 8;  // inverse-swizzled source granule
      async_copy16(Kh + (size_t)(k0 + row) * 64 + gs, &lds_k[bufi][slot * 8]);
      async_copy16(Vth + (size_t)row * 2048 + k0 + gs, &lds_vt[bufi][slot * 8]);
    }
    if (tid < 64) lds_biasf[bufi][tid] = pad[b * S + k0 + tid] ? 0.f : NEG;
    const int pvn = pad[b * S + k0 + lane];   // per-wave ballot source
    if (bufi) pv1 = pvn; else pv0 = pvn;
  };

  const int kend = q0 + 64;  // last k-tile origin (inclusive)
  stage(0, 0);
  __syncthreads();  // drains vmcnt(0): tile 0 resident
  int cur = 0;

  for (int k0 = 0; k0 <= kend; k0 += 64) {
    if (k0 < kend) stage(k0 + 64, cur ^ 1);  // prefetch next tile

    if (k0 <= qb + 31) {  // wave-uniform: skip fully-masked tiles
      const u16* lk = lds_k[cur];
      const u16* lvt = lds_vt[cur];
      const float* lb = lds_biasf[cur];
      const int pvc = cur ? pv1 : pv0;
      const bool fast = (__ballot(pvc != 0) == ~0ull);
      const bool needMask = (k0 + 63 > qb);
      const int thrh = qb + l31 - k0 - 4 * hi;  // mask iff rm+32*kt > thrh

      // ---- QK^T swapped: S[kpos][q], kpos reg-mapped, q = l31 ----
      f32x16 sacc0, sacc1;
#pragma unroll
      for (int r = 0; r < 16; ++r) { sacc0[r] = 0.f; sacc1[r] = 0.f; }
#pragma unroll
      for (int c = 0; c < 4; ++c) {
        const int gsw = ((2 * c + hi) ^ l7) * 8;
        bf16x8 kf0 = *(const bf16x8*)(lk + l31 * 64 + gsw);
        bf16x8 kf1 = *(const bf16x8*)(lk + (l31 + 32) * 64 + gsw);
        sacc0 = MFMA32(kf0, qfrag[c], sacc0);
        sacc1 = MFMA32(kf1, qfrag[c], sacc1);
      }

      // ---- softmax in-register + pack to PV A-frags ----
      bf16x8 pa[2][2];
#pragma unroll
      for (int kt = 0; kt < 2; ++kt) {
        float pe[16];
        if (fast) {
#pragma unroll
          for (int r = 0; r < 16; ++r) {
            float s = (kt == 0) ? sacc0[r] : sacc1[r];
            if (needMask) {
              const int rm = (r & 3) + 8 * (r >> 2) + 32 * kt;
              s = (rm > thrh) ? NEG : s;
            }
            pe[r] = __builtin_amdgcn_exp2f(s);
          }
        } else {
          f32x4 bv[4];
#pragma unroll
          for (int g = 0; g < 4; ++g)
            bv[g] = *(const f32x4*)(lb + g * 8 + 4 * hi + 32 * kt);
#pragma unroll
          for (int r = 0; r < 16; ++r) {
            float s = ((kt == 0) ? sacc0[r] : sacc1[r]) + bv[r >> 2][r & 3];
            if (needMask) {
              const int rm = (r & 3) + 8 * (r >> 2) + 32 * kt;
              s = (rm > thrh) ? NEG : s;
            }
            pe[r] = __builtin_amdgcn_exp2f(s);
          }
        }
        // words: {r0,r1},{r2,r3} | {r4,r5},{r6,r7}; swap assembles kpos order
        u32 a0 = cvt_pk_bf16(pe[0], pe[1]), a1 = cvt_pk_bf16(pe[2], pe[3]);
        u32 b0 = cvt_pk_bf16(pe[4], pe[5]), b1 = cvt_pk_bf16(pe[6], pe[7]);
        swap32(a0, b0);
        swap32(a1, b1);
        u32x4 w0 = {a0, a1, b0, b1};
        pa[kt][0] = __builtin_bit_cast(bf16x8, w0);
        u32 c0 = cvt_pk_bf16(pe[8], pe[9]), c1 = cvt_pk_bf16(pe[10], pe[11]);
        u32 d0 = cvt_pk_bf16(pe[12], pe[13]), d1 = cvt_pk_bf16(pe[14], pe[15]);
        swap32(c0, d0);
        swap32(c1, d1);
        u32x4 w1 = {c0, c1, d0, d1};
        pa[kt][1] = __builtin_bit_cast(bf16x8, w1);
      }

      // ---- PV + row-sum: O[q][d] and l[q], q reg-mapped ----
      __builtin_amdgcn_s_setprio(1);
#pragma unroll
      for (int kt = 0; kt < 2; ++kt)
#pragma unroll
        for (int ks = 0; ks < 2; ++ks) {
          const int kq = kt * 2 + ks;
          lacc = MFMA32(pa[kt][ks], ones, lacc);
          const int gsw = ((2 * kq + hi) ^ l7) * 8;
          bf16x8 vf0 = *(const bf16x8*)(lvt + l31 * 64 + gsw);
          bf16x8 vf1 = *(const bf16x8*)(lvt + (l31 + 32) * 64 + gsw);
          o_acc0 = MFMA32(pa[kt][ks], vf0, o_acc0);
          o_acc1 = MFMA32(pa[kt][ks], vf1, o_acc1);
        }
      __builtin_amdgcn_s_setprio(0);
    }

    __syncthreads();  // drains vmcnt(0) (prefetch landed) + all reads of cur done
    cur ^= 1;
  }

  // epilogue: normalize, write [B][S][H*64]
#pragma unroll
  for (int r = 0; r < 16; ++r) {
    const int q = qb + (r & 3) + 8 * (r >> 2) + 4 * hi;
    const float l = lacc[r];
    const float rl = (l > 0.f) ? (1.0f / l) : 0.f;
    O[(size_t)(b * S + q) * 1024 + h * 64 + l31] = f2bf(o_acc0[r] * rl);
    O[(size_t)(b * S + q) * 1024 + h * 64 + 32 + l31] = f2bf(o_acc1[r] * rl);
  }
}

// ---------- kernel 3: output projection (writes fp32 to d_out) ----------

__global__ __launch_bounds__(512, 2) void oproj_kernel(
    const u16* __restrict__ A, const u16* __restrict__ w_o, float* __restrict__ out) {
  __shared__ u16 lds[49152];
  f32x4 acc[4][4];
  const int row0 = blockIdx.y * 256;
  const int col0 = blockIdx.x * 128;
  gemm256_bt(A, w_o, row0, col0, lds, acc);
  const int tid = threadIdx.x;
  const int wave = tid >> 6, lane = tid & 63;
  const int fr = lane & 15, quad = lane >> 4;
  const int wm = (wave >> 1) * 64, wn = (wave & 1) * 64;
#pragma unroll
  for (int mt = 0; mt < 4; ++mt)
#pragma unroll
    for (int nt = 0; nt < 4; ++nt) {
      const int ncol = col0 + wn + nt * 16 + fr;
#pragma unroll
      for (int r = 0; r < 4; ++r) {
        const int mrow = row0 + wm + mt * 16 + quad * 4 + r;
        out[(size_t)mrow * 1024 + ncol] = acc[mt][nt][r];
      }
    }
}

// ---------- launch ----------

extern "C" void kernel_launch(void* const* d_in, const int* in_sizes, int n_in,
                              void* d_out, int out_size, void* d_ws, size_t ws_size,
                              hipStream_t stream) {
  const float* x_f = (const float*)d_in[0];     // [4][2048][1024] fp32
  const int* pad = (const int*)d_in[1];         // [4][2048] int32
  const float* wqkv_f = (const float*)d_in[2];  // [3072][1024] fp32
  const float* wo_f = (const float*)d_in[3];    // [1024][1024] fp32
  float* out = (float*)d_out;                   // [4][2048][1024] fp32

  const int NX = 4 * 2048 * 1024;
  const int NWQKV = 3072 * 1024;
  const int NWO = 1024 * 1024;
  const size_t HSZ = (size_t)4 * 16 * 2048 * 64;  // 8M elems per head-tensor

  u16* xb = (u16*)d_ws;            // 16 MB
  u16* wqkvb = xb + NX;            // 6 MB
  u16* wob = wqkvb + NWQKV;        // 2 MB
  u16* q_ws = wob + NWO;           // 16 MB  [B][H][S][64] (pre-scaled, roped)
  u16* k_ws = q_ws + HSZ;          // 16 MB  [B][H][S][64] (roped)
  u16* vt_ws = k_ws + HSZ;         // 16 MB  [B][H][64][S] (transposed)
  u16* attn_ws = vt_ws + HSZ;      // 16 MB  [B*S][D]
  float2* rope_t = (float2*)(attn_ws + HSZ);  // 512 KB [2048][32]

  prep_kernel<<<dim3(12544), dim3(256), 0, stream>>>(x_f, wqkv_f, wo_f, xb, wqkvb,
                                                     wob, rope_t);
  qkv_rope_kernel<<<dim3(24, 32), dim3(512), 0, stream>>>(xb, wqkvb, rope_t, q_ws,
                                                          k_ws, vt_ws);
  flash_attn_kernel<<<dim3(1024), dim3(256), 0, stream>>>(q_ws, k_ws, vt_ws, pad,
                                                          attn_ws);
  oproj_kernel<<<dim3(8, 32), dim3(512), 0, stream>>>(attn_ws, wob, out);
}